// Round 2
// baseline (1200.613 us; speedup 1.0000x reference)
//
#include <hip/hip_runtime.h>
#include <math.h>

#define TAU 0.07f
#define B_ 8
#define C_ 128
#define HW_ (512 * 512)
#define K_ 64
#define NNEG_ 7
#define P_ 4096
#define QB 4   // queries per block

__device__ inline float wave_reduce_sum(float v) {
    #pragma unroll
    for (int off = 32; off; off >>= 1) v += __shfl_xor(v, off, 64);
    return v;
}

__device__ inline unsigned long long wave_reduce_maxu64(unsigned long long v) {
    #pragma unroll
    for (int off = 32; off; off >>= 1) {
        unsigned long long o = __shfl_xor(v, off, 64);
        v = (o > v) ? o : v;
    }
    return v;
}

// One block (128 threads) per prototype: L2-normalize pos_pool rows and store
// TRANSPOSED into poolT[c * P + p] so the argmax kernel reads lane-consecutive
// prototypes (fully coalesced 1 KB bursts).
__global__ void normalize_transpose_kernel(const float* __restrict__ pool,
                                           float* __restrict__ poolT) {
    const int p = blockIdx.x;
    const int c = threadIdx.x;  // 128 threads
    __shared__ float red[2];
    float v = pool[p * C_ + c];
    float ws = wave_reduce_sum(v * v);
    if ((c & 63) == 0) red[c >> 6] = ws;
    __syncthreads();
    const float inv = 1.0f / fmaxf(sqrtf(red[0] + red[1]), 1e-12f);
    poolT[(size_t)c * P_ + p] = v * inv;
}

// One block (512 threads) per QB=4 queries. Pool reads amortized 4x:
// L2 traffic 1 GiB -> 256 MB (was the dominant ~30 us term).
__global__ void __launch_bounds__(512)
loss_kernel(const float* __restrict__ qf,     // [B, C, HW]
            const float* __restrict__ poolT,  // [C, P] normalized, transposed
            const float* __restrict__ neg,    // [B, K, N, C]
            const int* __restrict__ qidx,     // [B, K]
            float* __restrict__ out) {
    const int t = threadIdx.x;       // 0..511
    const int wid = t >> 6;          // 0..7
    const int lane = t & 63;
    const int bk0 = blockIdx.x * QB; // first query of this block

    __shared__ __align__(16) float qn[QB][C_];
    __shared__ unsigned long long redk[8][QB];
    __shared__ float lgsh[QB][1 + NNEG_];

    // ---- gather + normalize: wave w (< QB) handles query bk0+w ----
    if (wid < QB) {
        const int bk = bk0 + wid;
        const int b = bk >> 6;  // / K_
        const int idx = qidx[bk];
        const size_t base = (size_t)b * C_ * (size_t)HW_ + (size_t)idx;
        float2 v;
        v.x = qf[base + (size_t)(2 * lane) * HW_];
        v.y = qf[base + (size_t)(2 * lane + 1) * HW_];
        const float ss = wave_reduce_sum(v.x * v.x + v.y * v.y);
        const float inv = 1.0f / fmaxf(sqrtf(ss), 1e-12f);
        float2 o; o.x = v.x * inv; o.y = v.y * inv;
        ((float2*)qn[wid])[lane] = o;
    }
    __syncthreads();

    // ---- argmax over P prototypes for all QB queries ----
    // Thread t, pass j owns protos p = 4*(j*512+t)..+3 (2 passes).
    const float4* __restrict__ pT4 = (const float4*)poolT;  // [C_][P_/4]
    float best[QB];
    int bestp[QB];
    #pragma unroll
    for (int q = 0; q < QB; ++q) { best[q] = -3.0e38f; bestp[q] = 0; }

    #pragma unroll 1
    for (int j = 0; j < P_ / (512 * 4); ++j) {  // 2 passes
        float4 d[QB];
        #pragma unroll
        for (int q = 0; q < QB; ++q) { d[q].x = 0.f; d[q].y = 0.f; d[q].z = 0.f; d[q].w = 0.f; }
        const float4* __restrict__ col = pT4 + (size_t)j * 512 + t;
        #pragma unroll 2
        for (int cc = 0; cc < C_ / 4; ++cc) {
            const float4 v0 = col[(size_t)(4 * cc + 0) * (P_ / 4)];
            const float4 v1 = col[(size_t)(4 * cc + 1) * (P_ / 4)];
            const float4 v2 = col[(size_t)(4 * cc + 2) * (P_ / 4)];
            const float4 v3 = col[(size_t)(4 * cc + 3) * (P_ / 4)];
            #pragma unroll
            for (int q = 0; q < QB; ++q) {
                const float4 qv = ((const float4*)qn[q])[cc];  // LDS broadcast
                d[q].x += qv.x * v0.x + qv.y * v1.x + qv.z * v2.x + qv.w * v3.x;
                d[q].y += qv.x * v0.y + qv.y * v1.y + qv.z * v2.y + qv.w * v3.y;
                d[q].z += qv.x * v0.z + qv.y * v1.z + qv.z * v2.z + qv.w * v3.z;
                d[q].w += qv.x * v0.w + qv.y * v1.w + qv.z * v2.w + qv.w * v3.w;
            }
        }
        const int pb = (j * 512 + t) * 4;
        #pragma unroll
        for (int q = 0; q < QB; ++q) {
            // ascending p, strict > keeps the lowest index on ties
            if (d[q].x > best[q]) { best[q] = d[q].x; bestp[q] = pb + 0; }
            if (d[q].y > best[q]) { best[q] = d[q].y; bestp[q] = pb + 1; }
            if (d[q].z > best[q]) { best[q] = d[q].z; bestp[q] = pb + 2; }
            if (d[q].w > best[q]) { best[q] = d[q].w; bestp[q] = pb + 3; }
        }
    }
    // per-query (value, ~idx) key: max-key == (max value, lowest index)
    #pragma unroll
    for (int q = 0; q < QB; ++q) {
        unsigned int fu = __float_as_uint(best[q]);
        fu = (fu & 0x80000000u) ? ~fu : (fu | 0x80000000u);
        unsigned long long key =
            ((unsigned long long)fu << 32) | (unsigned int)(~(unsigned int)bestp[q]);
        key = wave_reduce_maxu64(key);
        if (lane == 0) redk[wid][q] = key;
    }

    // ---- negatives: 28 wave-local reductions strided over 8 waves ----
    for (int task = wid; task < QB * NNEG_; task += 8) {
        const int q = task / NNEG_;
        const int n = task - q * NNEG_;
        const int bk = bk0 + q;
        const float2 nv =
            ((const float2*)(neg + ((size_t)bk * NNEG_ + n) * C_))[lane];
        const float2 q2 = ((const float2*)qn[q])[lane];
        const float s1 = wave_reduce_sum(nv.x * nv.x + nv.y * nv.y);
        const float s2 = wave_reduce_sum(nv.x * q2.x + nv.y * q2.y);
        if (lane == 0)
            lgsh[q][1 + n] = (s2 / fmaxf(sqrtf(s1), 1e-12f)) * (1.0f / TAU);
    }
    __syncthreads();

    // ---- log-softmax CE, label 0; thread q finalizes query q ----
    if (t < QB) {
        const int q = t;
        unsigned long long k2 = redk[0][q];
        #pragma unroll
        for (int i = 1; i < 8; ++i) k2 = (redk[i][q] > k2) ? redk[i][q] : k2;
        unsigned int vu = (unsigned int)(k2 >> 32);
        vu = (vu & 0x80000000u) ? (vu ^ 0x80000000u) : ~vu;
        const float lg0 = __uint_as_float(vu) * (1.0f / TAU);  // pos logit
        float m = lg0;
        #pragma unroll
        for (int i = 1; i <= NNEG_; ++i) m = fmaxf(m, lgsh[q][i]);
        float se = expf(lg0 - m);
        #pragma unroll
        for (int i = 1; i <= NNEG_; ++i) se += expf(lgsh[q][i] - m);
        const float loss = (m + logf(se)) - lg0;
        atomicAdd(out, loss * (1.0f / (B_ * K_)));
    }
}

extern "C" void kernel_launch(void* const* d_in, const int* in_sizes, int n_in,
                              void* d_out, int out_size, void* d_ws, size_t ws_size,
                              hipStream_t stream) {
    const float* query_feat = (const float*)d_in[0];  // [B, C, H, W] fp32
    const float* pos_pool   = (const float*)d_in[1];  // [P, C] fp32
    const float* neg_protos = (const float*)d_in[2];  // [B, K, N, C] fp32
    const int*   query_idx  = (const int*)d_in[3];    // [B, K] int32
    float* out = (float*)d_out;                       // scalar fp32

    float* poolT = (float*)d_ws;  // P*C floats = 2 MB, [C][P] layout

    hipMemsetAsync(out, 0, sizeof(float) * out_size, stream);
    normalize_transpose_kernel<<<P_, C_, 0, stream>>>(pos_pool, poolT);
    loss_kernel<<<B_ * K_ / QB, 512, 0, stream>>>(query_feat, poolT, neg_protos,
                                                  query_idx, out);
}